// Round 1
// baseline (2455.693 us; speedup 1.0000x reference)
//
#include <hip/hip_runtime.h>
#include <hip/hip_bf16.h>
#include <stdint.h>

typedef _Float16 f16x8 __attribute__((ext_vector_type(8)));
typedef _Float16 f16x4 __attribute__((ext_vector_type(4)));
typedef float    f32x4 __attribute__((ext_vector_type(4)));

#define BM 128
#define BN 128
#define BK 64

// ---------------------------------------------------------------------------
// global->LDS direct load, 16B per lane. LDS dest must be wave-uniform base;
// HW adds lane*16. (CK-style addrspace cast through uintptr_t.)
// ---------------------------------------------------------------------------
__device__ __forceinline__ void gload_lds16(const void* g, void* l) {
  __builtin_amdgcn_global_load_lds(
      reinterpret_cast<const __attribute__((address_space(1))) void*>(
          reinterpret_cast<uintptr_t>(g)),
      reinterpret_cast<__attribute__((address_space(3))) void*>(
          reinterpret_cast<uintptr_t>(l)),
      16, 0, 0);
}

// XOR swizzle: rows 0..7 spread across the 128B row via bits 4..6.
// Involution (modifies only bits 4-6, keyed off bits 7-9). 16B-granular.
__device__ __forceinline__ int swz(int o) { return o ^ ((o >> 3) & 0x70); }

__device__ __forceinline__ f16x8 lds_frag(const _Float16* s, int row, int kbyte) {
  int o = swz(row * 128 + kbyte);
  return *reinterpret_cast<const f16x8*>(reinterpret_cast<const char*>(s) + o);
}

// ---------------------------------------------------------------------------
// prepass 1: edge_rep = relu(edge_ctx @ W_post_emb + b)   (1280x512 @ 512x1024)
// 8 rows per block, fp32.
// ---------------------------------------------------------------------------
__global__ void k_edge(const float* __restrict__ ec, const float* __restrict__ W,
                       const float* __restrict__ b, float* __restrict__ er)
{
  __shared__ float sec[8 * 512];
  const int t  = threadIdx.x;
  const int rb = blockIdx.x * 8;
#pragma unroll
  for (int j = 0; j < 16; ++j)
    sec[j * 256 + t] = ec[(size_t)rb * 512 + j * 256 + t];
  __syncthreads();

  const int c4 = t * 4;
  f32x4 acc[8];
#pragma unroll
  for (int r = 0; r < 8; ++r) acc[r] = f32x4{0.f, 0.f, 0.f, 0.f};

  for (int k = 0; k < 512; ++k) {
    f32x4 w = *reinterpret_cast<const f32x4*>(W + (size_t)k * 1024 + c4);
#pragma unroll
    for (int r = 0; r < 8; ++r) acc[r] += sec[r * 512 + k] * w;
  }
  f32x4 bb = *reinterpret_cast<const f32x4*>(b + c4);
#pragma unroll
  for (int r = 0; r < 8; ++r) {
    f32x4 o = acc[r] + bb;
#pragma unroll
    for (int i = 0; i < 4; ++i) o[i] = o[i] > 0.f ? o[i] : 0.f;
    *reinterpret_cast<f32x4*>(er + (size_t)(rb + r) * 1024 + c4) = o;
  }
}

// ---------------------------------------------------------------------------
// prepass 2: gather -> A_cat[r][c] = f16(edge_rep[(c<512?p0:p1)][c])
// ---------------------------------------------------------------------------
__global__ void k_gather(const float* __restrict__ er, const int* __restrict__ pidx,
                         _Float16* __restrict__ Acat)
{
  const int r  = blockIdx.x;
  const int c4 = threadIdx.x * 4;
  const int obj = pidx[2 * r + (c4 >= 512 ? 1 : 0)];
  f32x4 v = *reinterpret_cast<const f32x4*>(er + (size_t)obj * 1024 + c4);
  f16x4 h;
  h[0] = (_Float16)v[0]; h[1] = (_Float16)v[1];
  h[2] = (_Float16)v[2]; h[3] = (_Float16)v[3];
  *reinterpret_cast<f16x4*>(Acat + (size_t)r * 1024 + c4) = h;
}

// ---------------------------------------------------------------------------
// prepass 3: fp32 -> fp16 convert (union_features), 8 elems/thread
// ---------------------------------------------------------------------------
__global__ void k_cvt(const float* __restrict__ in, _Float16* __restrict__ out)
{
  const size_t g = (size_t)blockIdx.x * 256 + threadIdx.x;
  const f32x4* p = reinterpret_cast<const f32x4*>(in) + g * 2;
  f32x4 v0 = p[0], v1 = p[1];
  f16x8 h;
  h[0] = (_Float16)v0[0]; h[1] = (_Float16)v0[1];
  h[2] = (_Float16)v0[2]; h[3] = (_Float16)v0[3];
  h[4] = (_Float16)v1[0]; h[5] = (_Float16)v1[1];
  h[6] = (_Float16)v1[2]; h[7] = (_Float16)v1[3];
  *(reinterpret_cast<f16x8*>(out) + g) = h;
}

// ---------------------------------------------------------------------------
// prepass 4: Wt[n][k] = f16(W[k][n])  (tiled transpose via LDS)
// ---------------------------------------------------------------------------
__global__ void k_wt(const float* __restrict__ W, _Float16* __restrict__ Wt,
                     int K, int N)
{
  __shared__ float tile[64][65];
  const int ntn = N >> 6;
  const int kt = blockIdx.x / ntn, nt = blockIdx.x % ntn;
  const int tx = threadIdx.x & 63, ty = threadIdx.x >> 6;
  const int k0 = kt * 64, n0 = nt * 64;
#pragma unroll
  for (int j = 0; j < 16; ++j) {
    int kr = j * 4 + ty;
    tile[kr][tx] = W[(size_t)(k0 + kr) * N + n0 + tx];
  }
  __syncthreads();
#pragma unroll
  for (int j = 0; j < 16; ++j) {
    int nr = j * 4 + ty;
    Wt[(size_t)(n0 + nr) * K + k0 + tx] = (_Float16)tile[tx][nr];
  }
}

// ---------------------------------------------------------------------------
// main fused dual-GEMM: out = (Acat@Wc^T + bc) * (Auf@Wu^T + bu)
// 128x128 tile, BK=64, 512 threads (8 waves as 2x4), wave tile 64x32.
// ---------------------------------------------------------------------------
__device__ __forceinline__ void run_gemm(
    const _Float16* __restrict__ A, const _Float16* __restrict__ Bt, int K,
    _Float16* sA, _Float16* sB, int rowBase, int colBase,
    int wid, int lane, int wr, int wc, f32x4 (&acc)[4][2])
{
  const int lr = lane & 15, lg = lane >> 4;
  for (int kt = 0; kt < K; kt += BK) {
    // stage 16KB A-tile + 16KB B-tile (2 issues each, 512 thr x 16B)
#pragma unroll
    for (int j = 0; j < 2; ++j) {
      int o  = j * 8192 + wid * 1024 + lane * 16;   // linear LDS byte offset
      int op = swz(o);                              // logical (row,k) source
      int r  = op >> 7;
      int kh = (op & 127) >> 1;
      gload_lds16(A  + (size_t)(rowBase + r) * K + kt + kh, sA + (o - lane * 16) / 2);
      gload_lds16(Bt + (size_t)(colBase + r) * K + kt + kh, sB + (o - lane * 16) / 2);
    }
    __syncthreads();   // drains vmcnt(0) -> staged data visible
#pragma unroll
    for (int kk = 0; kk < 2; ++kk) {
      const int kbyte = kk * 64 + lg * 16;
      f16x8 af[4], bf[2];
#pragma unroll
      for (int m = 0; m < 4; ++m) af[m] = lds_frag(sA, wr * 64 + m * 16 + lr, kbyte);
#pragma unroll
      for (int n = 0; n < 2; ++n) bf[n] = lds_frag(sB, wc * 32 + n * 16 + lr, kbyte);
#pragma unroll
      for (int m = 0; m < 4; ++m)
#pragma unroll
        for (int n = 0; n < 2; ++n)
          acc[m][n] = __builtin_amdgcn_mfma_f32_16x16x32_f16(af[m], bf[n], acc[m][n], 0, 0, 0);
    }
    __syncthreads();   // protect LDS before next stage
  }
}

__global__ __launch_bounds__(512) void k_main(
    const _Float16* __restrict__ Acat, const _Float16* __restrict__ Auf,
    const _Float16* __restrict__ Btc,  const _Float16* __restrict__ Btu,
    const float* __restrict__ bcat, const float* __restrict__ bup,
    float* __restrict__ out)
{
  __shared__ __align__(16) char smem[32768];
  _Float16* sA = reinterpret_cast<_Float16*>(smem);
  _Float16* sB = reinterpret_cast<_Float16*>(smem + 16384);

  const int tid = threadIdx.x;
  const int lane = tid & 63, wid = tid >> 6;
  const int wr = wid >> 2, wc = wid & 3;          // 2x4 wave grid
  const int rowBase = blockIdx.y * BM;
  const int colBase = blockIdx.x * BN;
  const int lr = lane & 15, lg = lane >> 4;

  f32x4 accU[4][2] = {};
  f32x4 accP[4][2] = {};

  run_gemm(Auf,  Btu, 2048, sA, sB, rowBase, colBase, wid, lane, wr, wc, accU);
  run_gemm(Acat, Btc, 1024, sA, sB, rowBase, colBase, wid, lane, wr, wc, accP);

#pragma unroll
  for (int n = 0; n < 2; ++n) {
    const int col = colBase + wc * 32 + n * 16 + lr;
    const float bc = bcat[col], bu = bup[col];
#pragma unroll
    for (int m = 0; m < 4; ++m) {
      const int row0 = rowBase + wr * 64 + m * 16 + lg * 4;
#pragma unroll
      for (int i = 0; i < 4; ++i)
        out[(size_t)(row0 + i) * 4096 + col] = (accP[m][n][i] + bc) * (accU[m][n][i] + bu);
    }
  }
}

// ---------------------------------------------------------------------------
extern "C" void kernel_launch(void* const* d_in, const int* in_sizes, int n_in,
                              void* d_out, int out_size, void* d_ws, size_t ws_size,
                              hipStream_t stream)
{
  const float* edge_ctx = (const float*)d_in[0];
  const int*   pair_idx = (const int*)d_in[1];
  const float* uf       = (const float*)d_in[2];
  const float* Wpe      = (const float*)d_in[3];
  const float* bpe      = (const float*)d_in[4];
  const float* Wpc      = (const float*)d_in[5];
  const float* bpc      = (const float*)d_in[6];
  const float* Wup      = (const float*)d_in[7];
  const float* bup      = (const float*)d_in[8];
  float* out = (float*)d_out;

  char* ws = (char*)d_ws;
  float*    edge_rep = (float*)ws;                                   //  5,242,880 B
  _Float16* Acat = (_Float16*)(ws + 5242880);                        // 134,217,728 B
  _Float16* Auf  = (_Float16*)(ws + 5242880 + 134217728);            // 268,435,456 B
  _Float16* Btc  = (_Float16*)(ws + 5242880 + 134217728 + 268435456);          // 8,388,608 B
  _Float16* Btu  = (_Float16*)(ws + 5242880 + 134217728 + 268435456 + 8388608);// 16,777,216 B
  // total ws use: 433,061,888 B

  k_edge<<<160, 256, 0, stream>>>(edge_ctx, Wpe, bpe, edge_rep);
  k_wt<<<(1024 / 64) * (4096 / 64), 256, 0, stream>>>(Wpc, Btc, 1024, 4096);
  k_wt<<<(2048 / 64) * (4096 / 64), 256, 0, stream>>>(Wup, Btu, 2048, 4096);
  k_gather<<<65536, 256, 0, stream>>>(edge_rep, pair_idx, Acat);
  k_cvt<<<65536, 256, 0, stream>>>(uf, Auf);
  k_main<<<dim3(4096 / BN, 65536 / BM), 512, 0, stream>>>(Acat, Auf, Btc, Btu, bpc, bup, out);
}

// Round 2
// 2272.476 us; speedup vs baseline: 1.0806x; 1.0806x over previous
//
#include <hip/hip_runtime.h>
#include <hip/hip_bf16.h>
#include <stdint.h>

typedef _Float16 f16x8 __attribute__((ext_vector_type(8)));
typedef _Float16 f16x4 __attribute__((ext_vector_type(4)));
typedef float    f32x4 __attribute__((ext_vector_type(4)));

// ---------------------------------------------------------------------------
// global->LDS direct load, 16B per lane; LDS dest = wave-uniform base + lane*16
// ---------------------------------------------------------------------------
__device__ __forceinline__ void gload_lds16(const void* g, void* l) {
  __builtin_amdgcn_global_load_lds(
      reinterpret_cast<const __attribute__((address_space(1))) void*>(
          reinterpret_cast<uintptr_t>(g)),
      reinterpret_cast<__attribute__((address_space(3))) void*>(
          reinterpret_cast<uintptr_t>(l)),
      16, 0, 0);
}

// XOR swizzle within each 128B row, keyed off row&7 (bits 7-9 of byte offset).
__device__ __forceinline__ int swz(int o) { return o ^ ((o >> 3) & 0x70); }

// ---------------------------------------------------------------------------
// prepass 1: edge_rep = f16(relu(edge_ctx @ W_post_emb + b))  (1280x512x1024)
// ---------------------------------------------------------------------------
__global__ void k_edge(const float* __restrict__ ec, const float* __restrict__ W,
                       const float* __restrict__ b, _Float16* __restrict__ er)
{
  __shared__ float sec[8 * 512];
  const int t  = threadIdx.x;
  const int rb = blockIdx.x * 8;
#pragma unroll
  for (int j = 0; j < 16; ++j)
    sec[j * 256 + t] = ec[(size_t)rb * 512 + j * 256 + t];
  __syncthreads();

  const int c4 = t * 4;
  f32x4 acc[8];
#pragma unroll
  for (int r = 0; r < 8; ++r) acc[r] = f32x4{0.f, 0.f, 0.f, 0.f};

  for (int k = 0; k < 512; ++k) {
    f32x4 w = *reinterpret_cast<const f32x4*>(W + (size_t)k * 1024 + c4);
#pragma unroll
    for (int r = 0; r < 8; ++r) acc[r] += sec[r * 512 + k] * w;
  }
  f32x4 bb = *reinterpret_cast<const f32x4*>(b + c4);
#pragma unroll
  for (int r = 0; r < 8; ++r) {
    f32x4 o = acc[r] + bb;
    f16x4 h;
#pragma unroll
    for (int i = 0; i < 4; ++i) h[i] = (_Float16)(o[i] > 0.f ? o[i] : 0.f);
    *reinterpret_cast<f16x4*>(er + (size_t)(rb + r) * 1024 + c4) = h;
  }
}

// ---------------------------------------------------------------------------
// prepass 2: gather -> A_cat[r][c] = edge_rep[(c<512?p0:p1)][c]   (f16)
// ---------------------------------------------------------------------------
__global__ void k_gather(const _Float16* __restrict__ er, const int* __restrict__ pidx,
                         _Float16* __restrict__ Acat)
{
  const int r  = blockIdx.x;
  const int c4 = threadIdx.x * 4;
  const int obj = pidx[2 * r + (c4 >= 512 ? 1 : 0)];
  f16x4 v = *reinterpret_cast<const f16x4*>(er + (size_t)obj * 1024 + c4);
  *reinterpret_cast<f16x4*>(Acat + (size_t)r * 1024 + c4) = v;
}

// ---------------------------------------------------------------------------
// prepass 3: fp32 -> fp16 convert (union_features), 8 elems/thread
// ---------------------------------------------------------------------------
__global__ void k_cvt(const float* __restrict__ in, _Float16* __restrict__ out)
{
  const size_t g = (size_t)blockIdx.x * 256 + threadIdx.x;
  const f32x4* p = reinterpret_cast<const f32x4*>(in) + g * 2;
  f32x4 v0 = p[0], v1 = p[1];
  f16x8 h;
  h[0] = (_Float16)v0[0]; h[1] = (_Float16)v0[1];
  h[2] = (_Float16)v0[2]; h[3] = (_Float16)v0[3];
  h[4] = (_Float16)v1[0]; h[5] = (_Float16)v1[1];
  h[6] = (_Float16)v1[2]; h[7] = (_Float16)v1[3];
  *(reinterpret_cast<f16x8*>(out) + g) = h;
}

// ---------------------------------------------------------------------------
// prepass 4: Wt[n][k] = f16(W[k][n])  (tiled transpose via LDS)
// ---------------------------------------------------------------------------
__global__ void k_wt(const float* __restrict__ W, _Float16* __restrict__ Wt,
                     int K, int N)
{
  __shared__ float tile[64][65];
  const int ntn = N >> 6;
  const int kt = blockIdx.x / ntn, nt = blockIdx.x % ntn;
  const int tx = threadIdx.x & 63, ty = threadIdx.x >> 6;
  const int k0 = kt * 64, n0 = nt * 64;
#pragma unroll
  for (int j = 0; j < 16; ++j) {
    int kr = j * 4 + ty;
    tile[kr][tx] = W[(size_t)(k0 + kr) * N + n0 + tx];
  }
  __syncthreads();
#pragma unroll
  for (int j = 0; j < 16; ++j) {
    int nr = j * 4 + ty;
    Wt[(size_t)(n0 + nr) * K + k0 + tx] = (_Float16)tile[tx][nr];
  }
}

// ---------------------------------------------------------------------------
// main fused dual-GEMM: out = (Acat@Wc^T + bc) * (Auf@Wu^T + bu)
// BM=256 BN=128 BK=64, 512 thr = 8 waves (4x2), wave tile 64x64.
// Deep pipeline: counted vmcnt(4), 2 phases/K-tile, 16 MFMA/phase, setprio.
// Unified 48-tile K loop: tiles 0..31 = union (K=2048), 32..47 = cat (K=1024).
// ---------------------------------------------------------------------------
#define NT  48
#define NTU 32

template<int NI>
__device__ __forceinline__ void stage_tile(const _Float16* __restrict__ src, int ldk,
                                           int rcBase, int kt, _Float16* sbuf, int tid)
{
#pragma unroll
  for (int j = 0; j < NI; ++j) {
    int o  = j * 8192 + tid * 16;          // linear LDS byte offset
    int op = swz(o);                        // logical (row,kbyte) it must hold
    int r  = op >> 7;
    int kh = (op & 127) >> 1;
    gload_lds16(src + (size_t)(rcBase + r) * ldk + kt + kh,
                sbuf + (o - (tid & 63) * 16) / 2);   // wave-uniform base
  }
}

__device__ __forceinline__ void mfma16(f32x4 (&acc)[4][4], const f16x8 (&af)[4][2],
                                       const f16x8 (&bf)[2][2], int nh)
{
#pragma unroll
  for (int m = 0; m < 4; ++m)
#pragma unroll
    for (int nn = 0; nn < 2; ++nn)
#pragma unroll
      for (int kk = 0; kk < 2; ++kk)
        acc[m][nh * 2 + nn] = __builtin_amdgcn_mfma_f32_16x16x32_f16(
            af[m][kk], bf[nn][kk], acc[m][nh * 2 + nn], 0, 0, 0);
}

__global__ __launch_bounds__(512, 2) void k_main(
    const _Float16* __restrict__ Acat, const _Float16* __restrict__ Auf,
    const _Float16* __restrict__ Btc,  const _Float16* __restrict__ Btu,
    const float* __restrict__ bcat, const float* __restrict__ bup,
    float* __restrict__ out)
{
  extern __shared__ char smem[];                    // 96 KiB dynamic
  _Float16* sA = reinterpret_cast<_Float16*>(smem);            // 2 x 32KB
  _Float16* sB = reinterpret_cast<_Float16*>(smem + 65536);    // 2 x 16KB

  const int tid  = threadIdx.x;
  const int lane = tid & 63, lr = lane & 15, lg = lane >> 4;
  const int wid  = tid >> 6, wr = wid >> 1, wc = wid & 1;      // 4x2 wave grid

  // XCD-aware block swizzle: 8192 blocks, 1024/XCD chunks, then (rb, cb)
  const int bid = blockIdx.x;
  const int swb = (bid & 7) * 1024 + (bid >> 3);
  const int rowBase = (swb >> 5) * 256;
  const int colBase = (swb & 31) * 128;

  // per-thread swizzled LDS read offsets
  const int key  = (lr & 7) << 4;
  int kb[2];
  kb[0] = (lg * 16) ^ key;
  kb[1] = (64 + lg * 16) ^ key;
  const int arow = (wr * 64 + lr) * 128;
  const int brow = (wc * 64 + lr) * 128;

  f16x8 af[4][2], bf[2][2];
  f32x4 accU[4][4] = {};
  f32x4 accP[4][4] = {};

  // prologue: stage tile 0 (buffer 0)
  stage_tile<4>(Auf, 2048, rowBase, 0, sA, tid);
  stage_tile<2>(Btu, 2048, colBase, 0, sB, tid);

  for (int t = 0; t < NT; ++t) {
    const int cur = t & 1;
    _Float16* sAc = sA + cur * 16384;       // f16 units (32KB buffers)
    _Float16* sAn = sA + (cur ^ 1) * 16384;
    _Float16* sBc = sB + cur * 8192;        // f16 units (16KB buffers)
    _Float16* sBn = sB + (cur ^ 1) * 8192;

    // ---------------- phase A ----------------
    if (t + 1 < NT) {
      const int tt = t + 1;
      if (tt < NTU) stage_tile<4>(Auf,  2048, rowBase, tt * 64, sAn, tid);
      else          stage_tile<4>(Acat, 1024, rowBase, (tt - NTU) * 64, sAn, tid);
      asm volatile("s_waitcnt vmcnt(4)" ::: "memory");   // tile t's 6 loads done
    } else {
      asm volatile("s_waitcnt vmcnt(0)" ::: "memory");
    }
    __builtin_amdgcn_s_barrier();
    __builtin_amdgcn_sched_barrier(0);

    const char* a8 = reinterpret_cast<const char*>(sAc) + arow;
    const char* b8 = reinterpret_cast<const char*>(sBc) + brow;
#pragma unroll
    for (int m = 0; m < 4; ++m)
#pragma unroll
      for (int kk = 0; kk < 2; ++kk)
        af[m][kk] = *reinterpret_cast<const f16x8*>(a8 + m * 2048 + kb[kk]);
#pragma unroll
    for (int nn = 0; nn < 2; ++nn)
#pragma unroll
      for (int kk = 0; kk < 2; ++kk)
        bf[nn][kk] = *reinterpret_cast<const f16x8*>(b8 + nn * 2048 + kb[kk]);
    asm volatile("s_waitcnt lgkmcnt(0)" ::: "memory");
    __builtin_amdgcn_sched_barrier(0);
    __builtin_amdgcn_s_setprio(1);
    if (t < NTU) mfma16(accU, af, bf, 0);
    else         mfma16(accP, af, bf, 0);
    __builtin_amdgcn_s_setprio(0);

    // ---------------- phase B ----------------
    if (t + 1 < NT) {
      const int tt = t + 1;
      if (tt < NTU) stage_tile<2>(Btu, 2048, colBase, tt * 64, sBn, tid);
      else          stage_tile<2>(Btc, 1024, colBase, (tt - NTU) * 64, sBn, tid);
    }
#pragma unroll
    for (int nn = 0; nn < 2; ++nn)
#pragma unroll
      for (int kk = 0; kk < 2; ++kk)
        bf[nn][kk] = *reinterpret_cast<const f16x8*>(b8 + (2 + nn) * 2048 + kb[kk]);
    asm volatile("s_waitcnt lgkmcnt(0)" ::: "memory");
    __builtin_amdgcn_sched_barrier(0);
    __builtin_amdgcn_s_setprio(1);
    if (t < NTU) mfma16(accU, af, bf, 1);
    else         mfma16(accP, af, bf, 1);
    __builtin_amdgcn_s_setprio(0);
    __builtin_amdgcn_s_barrier();          // all reads of buffer cur complete
    __builtin_amdgcn_sched_barrier(0);
  }

  // ---------------- epilogue ----------------
#pragma unroll
  for (int n = 0; n < 4; ++n) {
    const int col = colBase + wc * 64 + n * 16 + lr;
    const float bc = bcat[col], bu = bup[col];
#pragma unroll
    for (int m = 0; m < 4; ++m) {
      const int row0 = rowBase + wr * 64 + m * 16 + lg * 4;
#pragma unroll
      for (int i = 0; i < 4; ++i)
        out[(size_t)(row0 + i) * 4096 + col] =
            (accP[m][n][i] + bc) * (accU[m][n][i] + bu);
    }
  }
}

// ---------------------------------------------------------------------------
extern "C" void kernel_launch(void* const* d_in, const int* in_sizes, int n_in,
                              void* d_out, int out_size, void* d_ws, size_t ws_size,
                              hipStream_t stream)
{
  const float* edge_ctx = (const float*)d_in[0];
  const int*   pair_idx = (const int*)d_in[1];
  const float* uf       = (const float*)d_in[2];
  const float* Wpe      = (const float*)d_in[3];
  const float* bpe      = (const float*)d_in[4];
  const float* Wpc      = (const float*)d_in[5];
  const float* bpc      = (const float*)d_in[6];
  const float* Wup      = (const float*)d_in[7];
  const float* bup      = (const float*)d_in[8];
  float* out = (float*)d_out;

  char* ws = (char*)d_ws;
  _Float16* edge_rep = (_Float16*)ws;                                // 2.6 MB region (use 5MB slot)
  _Float16* Acat = (_Float16*)(ws + 5242880);                        // 128 MB
  _Float16* Auf  = (_Float16*)(ws + 5242880 + 134217728);            // 256 MB
  _Float16* Btc  = (_Float16*)(ws + 5242880 + 134217728 + 268435456);           // 8 MB
  _Float16* Btu  = (_Float16*)(ws + 5242880 + 134217728 + 268435456 + 8388608); // 16 MB

  static int lds_attr_set = 0;
  (void)lds_attr_set;
  hipFuncSetAttribute((const void*)k_main,
                      hipFuncAttributeMaxDynamicSharedMemorySize, 98304);

  k_edge<<<160, 256, 0, stream>>>(edge_ctx, Wpe, bpe, edge_rep);
  k_wt<<<(1024 / 64) * (4096 / 64), 256, 0, stream>>>(Wpc, Btc, 1024, 4096);
  k_wt<<<(2048 / 64) * (4096 / 64), 256, 0, stream>>>(Wup, Btu, 2048, 4096);
  k_gather<<<65536, 256, 0, stream>>>(edge_rep, pair_idx, Acat);
  k_cvt<<<65536, 256, 0, stream>>>(uf, Auf);
  k_main<<<8192, 512, 98304, stream>>>(Acat, Auf, Btc, Btu, bpc, bup, out);
}

// Round 3
// 2169.219 us; speedup vs baseline: 1.1321x; 1.0476x over previous
//
#include <hip/hip_runtime.h>
#include <hip/hip_bf16.h>
#include <stdint.h>

typedef _Float16 f16x8 __attribute__((ext_vector_type(8)));
typedef _Float16 f16x4 __attribute__((ext_vector_type(4)));
typedef float    f32x4 __attribute__((ext_vector_type(4)));

// ---------------------------------------------------------------------------
// global->LDS direct load, 16B per lane; LDS dest = wave-uniform base + lane*16
// ---------------------------------------------------------------------------
__device__ __forceinline__ void gload_lds16(const void* g, void* l) {
  __builtin_amdgcn_global_load_lds(
      reinterpret_cast<const __attribute__((address_space(1))) void*>(
          reinterpret_cast<uintptr_t>(g)),
      reinterpret_cast<__attribute__((address_space(3))) void*>(
          reinterpret_cast<uintptr_t>(l)),
      16, 0, 0);
}

// XOR swizzle within each 128B row, keyed off row&7 (bits 7-9 of byte offset).
__device__ __forceinline__ int swz(int o) { return o ^ ((o >> 3) & 0x70); }

// ---------------------------------------------------------------------------
// prepass 1: edge_rep = f16(relu(edge_ctx @ W_post_emb + b))  (1280x512x1024)
// ---------------------------------------------------------------------------
__global__ void k_edge(const float* __restrict__ ec, const float* __restrict__ W,
                       const float* __restrict__ b, _Float16* __restrict__ er)
{
  __shared__ float sec[8 * 512];
  const int t  = threadIdx.x;
  const int rb = blockIdx.x * 8;
#pragma unroll
  for (int j = 0; j < 16; ++j)
    sec[j * 256 + t] = ec[(size_t)rb * 512 + j * 256 + t];
  __syncthreads();

  const int c4 = t * 4;
  f32x4 acc[8];
#pragma unroll
  for (int r = 0; r < 8; ++r) acc[r] = f32x4{0.f, 0.f, 0.f, 0.f};

  for (int k = 0; k < 512; ++k) {
    f32x4 w = *reinterpret_cast<const f32x4*>(W + (size_t)k * 1024 + c4);
#pragma unroll
    for (int r = 0; r < 8; ++r) acc[r] += sec[r * 512 + k] * w;
  }
  f32x4 bb = *reinterpret_cast<const f32x4*>(b + c4);
#pragma unroll
  for (int r = 0; r < 8; ++r) {
    f32x4 o = acc[r] + bb;
    f16x4 h;
#pragma unroll
    for (int i = 0; i < 4; ++i) h[i] = (_Float16)(o[i] > 0.f ? o[i] : 0.f);
    *reinterpret_cast<f16x4*>(er + (size_t)(rb + r) * 1024 + c4) = h;
  }
}

// ---------------------------------------------------------------------------
// prepass 2: gather -> A_cat[r][c] = edge_rep[(c<512?p0:p1)][c]   (f16)
// ---------------------------------------------------------------------------
__global__ void k_gather(const _Float16* __restrict__ er, const int* __restrict__ pidx,
                         _Float16* __restrict__ Acat)
{
  const int r  = blockIdx.x;
  const int c4 = threadIdx.x * 4;
  const int obj = pidx[2 * r + (c4 >= 512 ? 1 : 0)];
  f16x4 v = *reinterpret_cast<const f16x4*>(er + (size_t)obj * 1024 + c4);
  *reinterpret_cast<f16x4*>(Acat + (size_t)r * 1024 + c4) = v;
}

// ---------------------------------------------------------------------------
// prepass 3: fp32 -> fp16 convert (union_features), 8 elems/thread
// ---------------------------------------------------------------------------
__global__ void k_cvt(const float* __restrict__ in, _Float16* __restrict__ out)
{
  const size_t g = (size_t)blockIdx.x * 256 + threadIdx.x;
  const f32x4* p = reinterpret_cast<const f32x4*>(in) + g * 2;
  f32x4 v0 = p[0], v1 = p[1];
  f16x8 h;
  h[0] = (_Float16)v0[0]; h[1] = (_Float16)v0[1];
  h[2] = (_Float16)v0[2]; h[3] = (_Float16)v0[3];
  h[4] = (_Float16)v1[0]; h[5] = (_Float16)v1[1];
  h[6] = (_Float16)v1[2]; h[7] = (_Float16)v1[3];
  *(reinterpret_cast<f16x8*>(out) + g) = h;
}

// ---------------------------------------------------------------------------
// prepass 4: Wt[n][k] = f16(W[k][n])  (tiled transpose via LDS)
// ---------------------------------------------------------------------------
__global__ void k_wt(const float* __restrict__ W, _Float16* __restrict__ Wt,
                     int K, int N)
{
  __shared__ float tile[64][65];
  const int ntn = N >> 6;
  const int kt = blockIdx.x / ntn, nt = blockIdx.x % ntn;
  const int tx = threadIdx.x & 63, ty = threadIdx.x >> 6;
  const int k0 = kt * 64, n0 = nt * 64;
#pragma unroll
  for (int j = 0; j < 16; ++j) {
    int kr = j * 4 + ty;
    tile[kr][tx] = W[(size_t)(k0 + kr) * N + n0 + tx];
  }
  __syncthreads();
#pragma unroll
  for (int j = 0; j < 16; ++j) {
    int nr = j * 4 + ty;
    Wt[(size_t)(n0 + nr) * K + k0 + tx] = (_Float16)tile[tx][nr];
  }
}

// ---------------------------------------------------------------------------
// main fused dual-GEMM: out = (Acat@Wc^T + bc) * (Auf@Wu^T + bu)
// BM=256 BN=128 BK=64, 512 thr = 8 waves (4x2), wave tile 64x64.
// 3-buffer LDS, depth-2 prefetch, ONE barrier/tile, counted vmcnt(6).
// Unified 48-tile K loop: tiles 0..31 = union (K=2048), 32..47 = cat (K=1024).
// ---------------------------------------------------------------------------
#define NT  48
#define NTU 32

template<int NI>
__device__ __forceinline__ void stage_tile(const _Float16* __restrict__ src, int ldk,
                                           int rcBase, int kt, _Float16* sbuf, int tid)
{
#pragma unroll
  for (int j = 0; j < NI; ++j) {
    int o  = j * 8192 + tid * 16;          // linear LDS byte offset
    int op = swz(o);                        // logical (row,kbyte) it must hold
    int r  = op >> 7;
    int kh = (op & 127) >> 1;
    gload_lds16(src + (size_t)(rcBase + r) * ldk + kt + kh,
                sbuf + (o - (tid & 63) * 16) / 2);   // wave-uniform base
  }
}

__device__ __forceinline__ void mfma16(f32x4 (&acc)[4][4], const f16x8 (&af)[4][2],
                                       const f16x8 (&bf)[2][2], int nh)
{
#pragma unroll
  for (int m = 0; m < 4; ++m)
#pragma unroll
    for (int nn = 0; nn < 2; ++nn)
#pragma unroll
      for (int kk = 0; kk < 2; ++kk)
        acc[m][nh * 2 + nn] = __builtin_amdgcn_mfma_f32_16x16x32_f16(
            af[m][kk], bf[nn][kk], acc[m][nh * 2 + nn], 0, 0, 0);
}

__global__ __launch_bounds__(512, 2) void k_main(
    const _Float16* __restrict__ Acat, const _Float16* __restrict__ Auf,
    const _Float16* __restrict__ Btc,  const _Float16* __restrict__ Btu,
    const float* __restrict__ bcat, const float* __restrict__ bup,
    float* __restrict__ out)
{
  extern __shared__ char smem[];                    // 144 KiB dynamic
  // 3 x (32KB A + 16KB B)
  _Float16* bufA[3] = { reinterpret_cast<_Float16*>(smem),
                        reinterpret_cast<_Float16*>(smem + 32768),
                        reinterpret_cast<_Float16*>(smem + 65536) };
  _Float16* bufB[3] = { reinterpret_cast<_Float16*>(smem + 98304),
                        reinterpret_cast<_Float16*>(smem + 98304 + 16384),
                        reinterpret_cast<_Float16*>(smem + 98304 + 32768) };

  const int tid  = threadIdx.x;
  const int lane = tid & 63, lr = lane & 15, lg = lane >> 4;
  const int wid  = tid >> 6, wr = wid >> 1, wc = wid & 1;      // 4x2 wave grid

  // XCD-aware block swizzle: 8192 blocks, 1024/XCD chunks, then (rb, cb)
  const int bid = blockIdx.x;
  const int swb = (bid & 7) * 1024 + (bid >> 3);
  const int rowBase = (swb >> 5) * 256;
  const int colBase = (swb & 31) * 128;

  // per-thread swizzled LDS read offsets
  const int key  = (lr & 7) << 4;
  int kb[2];
  kb[0] = (lg * 16) ^ key;
  kb[1] = (64 + lg * 16) ^ key;
  const int arow = (wr * 64 + lr) * 128;
  const int brow = (wc * 64 + lr) * 128;

  f16x8 af[4][2], bf[2][2];
  f32x4 accU[4][4] = {};
  f32x4 accP[4][4] = {};

  // rotating buffer pointers: cur = tile t, nxt = t+1, fre = stage target (t+2)
  _Float16 *Ac = bufA[0], *An = bufA[1], *Af = bufA[2];
  _Float16 *Bc = bufB[0], *Bn = bufB[1], *Bf = bufB[2];

  // prologue: stage tiles 0 and 1 (order: A(4) then B(2) per tile)
  stage_tile<4>(Auf, 2048, rowBase, 0,  Ac, tid);
  stage_tile<2>(Btu, 2048, colBase, 0,  Bc, tid);
  stage_tile<4>(Auf, 2048, rowBase, 64, An, tid);
  stage_tile<2>(Btu, 2048, colBase, 64, Bn, tid);

  for (int t = 0; t < NT; ++t) {
    // wait for tile t's 6 loads (t+1's 6 stay in flight); drain fully at end
    if (t < NT - 1) asm volatile("s_waitcnt vmcnt(6)" ::: "memory");
    else            asm volatile("s_waitcnt vmcnt(0)" ::: "memory");
    __builtin_amdgcn_s_barrier();     // tile t visible to all; buffer Af free
    __builtin_amdgcn_sched_barrier(0);

    // stage tile t+2 into the free buffer (A first, then B, 6 loads total)
    if (t + 2 < NT) {
      const int tt = t + 2;
      if (tt < NTU) stage_tile<4>(Auf,  2048, rowBase, tt * 64, Af, tid);
      else          stage_tile<4>(Acat, 1024, rowBase, (tt - NTU) * 64, Af, tid);
    }

    const char* a8 = reinterpret_cast<const char*>(Ac) + arow;
    const char* b8 = reinterpret_cast<const char*>(Bc) + brow;
#pragma unroll
    for (int m = 0; m < 4; ++m)
#pragma unroll
      for (int kk = 0; kk < 2; ++kk)
        af[m][kk] = *reinterpret_cast<const f16x8*>(a8 + m * 2048 + kb[kk]);
#pragma unroll
    for (int nn = 0; nn < 2; ++nn)
#pragma unroll
      for (int kk = 0; kk < 2; ++kk)
        bf[nn][kk] = *reinterpret_cast<const f16x8*>(b8 + nn * 2048 + kb[kk]);

    if (t + 2 < NT) {
      const int tt = t + 2;
      if (tt < NTU) stage_tile<2>(Btu, 2048, colBase, tt * 64, Bf, tid);
      else          stage_tile<2>(Btc, 1024, colBase, (tt - NTU) * 64, Bf, tid);
    }

    asm volatile("s_waitcnt lgkmcnt(0)" ::: "memory");
    __builtin_amdgcn_sched_barrier(0);
    __builtin_amdgcn_s_setprio(1);
    if (t < NTU) mfma16(accU, af, bf, 0);
    else         mfma16(accP, af, bf, 0);
    __builtin_amdgcn_s_setprio(0);

#pragma unroll
    for (int nn = 0; nn < 2; ++nn)
#pragma unroll
      for (int kk = 0; kk < 2; ++kk)
        bf[nn][kk] = *reinterpret_cast<const f16x8*>(b8 + (2 + nn) * 2048 + kb[kk]);
    asm volatile("s_waitcnt lgkmcnt(0)" ::: "memory");
    __builtin_amdgcn_sched_barrier(0);
    __builtin_amdgcn_s_setprio(1);
    if (t < NTU) mfma16(accU, af, bf, 1);
    else         mfma16(accP, af, bf, 1);
    __builtin_amdgcn_s_setprio(0);
    __builtin_amdgcn_sched_barrier(0);

    // rotate buffers (no second barrier: reuse protected by next-iter barrier)
    _Float16* tA = Ac; Ac = An; An = Af; Af = tA;
    _Float16* tB = Bc; Bc = Bn; Bn = Bf; Bf = tB;
  }

  // ---------------- epilogue ----------------
#pragma unroll
  for (int n = 0; n < 4; ++n) {
    const int col = colBase + wc * 64 + n * 16 + lr;
    const float bc = bcat[col], bu = bup[col];
#pragma unroll
    for (int m = 0; m < 4; ++m) {
      const int row0 = rowBase + wr * 64 + m * 16 + lg * 4;
#pragma unroll
      for (int i = 0; i < 4; ++i)
        out[(size_t)(row0 + i) * 4096 + col] =
            (accP[m][n][i] + bc) * (accU[m][n][i] + bu);
    }
  }
}

// ---------------------------------------------------------------------------
extern "C" void kernel_launch(void* const* d_in, const int* in_sizes, int n_in,
                              void* d_out, int out_size, void* d_ws, size_t ws_size,
                              hipStream_t stream)
{
  const float* edge_ctx = (const float*)d_in[0];
  const int*   pair_idx = (const int*)d_in[1];
  const float* uf       = (const float*)d_in[2];
  const float* Wpe      = (const float*)d_in[3];
  const float* bpe      = (const float*)d_in[4];
  const float* Wpc      = (const float*)d_in[5];
  const float* bpc      = (const float*)d_in[6];
  const float* Wup      = (const float*)d_in[7];
  const float* bup      = (const float*)d_in[8];
  float* out = (float*)d_out;

  char* ws = (char*)d_ws;
  _Float16* edge_rep = (_Float16*)ws;                                // 2.6 MB region
  _Float16* Acat = (_Float16*)(ws + 5242880);                        // 128 MB
  _Float16* Auf  = (_Float16*)(ws + 5242880 + 134217728);            // 256 MB
  _Float16* Btc  = (_Float16*)(ws + 5242880 + 134217728 + 268435456);           // 8 MB
  _Float16* Btu  = (_Float16*)(ws + 5242880 + 134217728 + 268435456 + 8388608); // 16 MB

  hipFuncSetAttribute((const void*)k_main,
                      hipFuncAttributeMaxDynamicSharedMemorySize, 147456);

  k_edge<<<160, 256, 0, stream>>>(edge_ctx, Wpe, bpe, edge_rep);
  k_wt<<<(1024 / 64) * (4096 / 64), 256, 0, stream>>>(Wpc, Btc, 1024, 4096);
  k_wt<<<(2048 / 64) * (4096 / 64), 256, 0, stream>>>(Wup, Btu, 2048, 4096);
  k_gather<<<65536, 256, 0, stream>>>(edge_rep, pair_idx, Acat);
  k_cvt<<<65536, 256, 0, stream>>>(uf, Auf);
  k_main<<<8192, 512, 147456, stream>>>(Acat, Auf, Btc, Btu, bpc, bup, out);
}